// Round 5
// baseline (287.244 us; speedup 1.0000x reference)
//
#include <hip/hip_runtime.h>
#include <stdint.h>

// SimpleMarkovModel: 2-state Markov chain, 200000 emitters x 500 frames.
// Bit-exact JAX partitionable Threefry-2x32 (verified rounds 1-4, absmax 0).
//
// R5: attack the phantom 800 MB FETCH_SIZE (write-allocate/RFO on scattered
// dword stores). Each thread owns TWO CONSECUTIVE emitters (2t, 2t+1) and
// writes one dwordx2 per frame: 8 B/lane -> 512 B contiguous line-aligned
// per wave, instead of two 256 B dword stores 800 KB apart. Dual-chain ILP
// and wave count (1563) unchanged; subkey path = lean rolling uint2 s_load.

#define ROTL32(x, d) __builtin_amdgcn_alignbit((x), (x), 32 - (d))

__device__ __forceinline__ void tf2x32(uint32_t k0, uint32_t k1,
                                       uint32_t x0, uint32_t x1,
                                       uint32_t& o0, uint32_t& o1) {
  const uint32_t k2 = k0 ^ k1 ^ 0x1BD11BDAu;
  x0 += k0; x1 += k1;
#define TF_R(d) { x0 += x1; x1 = ROTL32(x1, d) ^ x0; }
  TF_R(13) TF_R(15) TF_R(26) TF_R(6)
  x0 += k1; x1 += k2 + 1u;
  TF_R(17) TF_R(29) TF_R(16) TF_R(24)
  x0 += k2; x1 += k0 + 2u;
  TF_R(13) TF_R(15) TF_R(26) TF_R(6)
  x0 += k0; x1 += k1 + 3u;
  TF_R(17) TF_R(29) TF_R(16) TF_R(24)
  x0 += k1; x1 += k2 + 4u;
  TF_R(13) TF_R(15) TF_R(26) TF_R(6)
  x0 += k2; x1 += k0 + 5u;
#undef TF_R
  o0 = x0; o1 = x1;
}

__global__ void subkeys_kernel(uint2* __restrict__ ks, int nf) {
  const int f = blockIdx.x * blockDim.x + threadIdx.x;
  if (f < nf) {
    uint32_t a, b;
    tf2x32(0u, 42u, 0u, (uint32_t)f, a, b);
    ks[f] = make_uint2(a, b);
  } else if (f == nf) {
    ks[f] = make_uint2(0u, 0u);  // pad: prefetch never branches
  }
}

__device__ __forceinline__ void markov_body(
    const float* __restrict__ initial, const float* __restrict__ transition,
    const float* __restrict__ tmat, const uint2* __restrict__ ks,
    float* __restrict__ out, int N, int nf) {
  const int t = blockIdx.x * blockDim.x + threadIdx.x;
  const int nA = 2 * t;          // two consecutive emitters per thread
  const int nB = 2 * t + 1;
  if (nA >= N) return;
  const bool hasB = (nB < N);    // false only for odd-N tail lane

  // u < p  <=>  bits < (ceil(p*2^23) << 9); clamp guards p ~ 1.0.
  const uint64_t t0w = ((uint64_t)(uint32_t)ceilf(transition[1] * 8388608.0f)) << 9;
  const uint64_t t1w = ((uint64_t)(uint32_t)ceilf(transition[3] * 8388608.0f)) << 9;
  const uint32_t tsh0 = (t0w > 0xFFFFFFFFull) ? 0xFFFFFFFFu : (uint32_t)t0w;
  const uint32_t tsh1 = (t1w > 0xFFFFFFFFull) ? 0xFFFFFFFFu : (uint32_t)t1w;
  const uint32_t sw0 = (tmat[1] != 0.0f) ? 1u : 0u;  // matrix 0 swaps?
  const uint32_t sw1 = (tmat[5] != 0.0f) ? 1u : 0u;  // matrix 1 swaps?

  uint32_t sA = (initial[2 * nA] != 0.0f) ? 0u : 1u;
  uint32_t sB = hasB ? ((initial[2 * nB] != 0.0f) ? 0u : 1u) : 0u;
  uint32_t thrA = sA ? tsh1 : tsh0;
  uint32_t thrB = sB ? tsh1 : tsh0;
  const uint32_t baseA = 2u * (uint32_t)nA;   // threefry counter = 2n + s
  const uint32_t baseB = 2u * (uint32_t)nB;

  float* op = out + nA;  // advances by N per frame; lane offset fixed
  uint2 ck = ks[0];
  for (int f = 0; f < nf; ++f) {
    const uint32_t k0 = ck.x, k1 = ck.y;
    ck = ks[f + 1];  // uniform rolling prefetch (padded at f == nf-1)
    const uint32_t k2 = k0 ^ k1 ^ 0x1BD11BDAu;
    const uint32_t c1 = k2 + 1u, c2 = k0 + 2u, c3 = k1 + 3u,
                   c4 = k2 + 4u, c5 = k0 + 5u;

    uint32_t xa0 = k0, xa1 = baseA + sA + k1;   // v_add3
    uint32_t xb0 = k0, xb1 = baseB + sB + k1;

#define RND(d) { xa0 += xa1; xa1 = ROTL32(xa1, (d)) ^ xa0;   \
                 xb0 += xb1; xb1 = ROTL32(xb1, (d)) ^ xb0; }
    RND(13) RND(15) RND(26) RND(6)
    xa0 += k1; xa1 += c1; xb0 += k1; xb1 += c1;
    RND(17) RND(29) RND(16) RND(24)
    xa0 += k2; xa1 += c2; xb0 += k2; xb1 += c2;
    RND(13) RND(15) RND(26) RND(6)
    xa0 += k0; xa1 += c3; xb0 += k0; xb1 += c3;
    RND(17) RND(29) RND(16) RND(24)
    xa0 += k1; xa1 += c4; xb0 += k1; xb1 += c4;
    RND(13) RND(15) RND(26) RND(6)
    xa0 += k2; xa1 += c5; xb0 += k2; xb1 += c5;
#undef RND

    sA ^= ((xa0 ^ xa1) < thrA) ? sw1 : sw0;
    sB ^= ((xb0 ^ xb1) < thrB) ? sw1 : sw0;
    thrA = sA ? tsh1 : tsh0;
    thrB = sB ? tsh1 : tsh0;

    if (hasB) {
      // one 8B line-aligned store per frame: {outA, outB}
      uint2 v;
      v.x = sA ? 0u : 0x3f800000u;
      v.y = sB ? 0u : 0x3f800000u;
      *(uint2*)op = v;
    } else {
      *(uint32_t*)op = sA ? 0u : 0x3f800000u;
    }
    op += N;
  }
}

__global__ __launch_bounds__(64) void markov_kernel(
    const float* __restrict__ initial, const float* __restrict__ transition,
    const float* __restrict__ tmat, const uint2* __restrict__ ks,
    float* __restrict__ out, int N, int nf) {
  markov_body(initial, transition, tmat, ks, out, N, nf);
}

// Fallback if d_ws too small: subkeys in LDS (same padded layout).
__global__ __launch_bounds__(64) void markov_kernel_lds(
    const float* __restrict__ initial, const float* __restrict__ transition,
    const float* __restrict__ tmat, float* __restrict__ out,
    int N, int nf) {
  extern __shared__ uint2 kf[];
  for (int f = threadIdx.x; f <= nf; f += blockDim.x) {
    uint2 k = make_uint2(0u, 0u);
    if (f < nf) {
      uint32_t a, b;
      tf2x32(0u, 42u, 0u, (uint32_t)f, a, b);
      k = make_uint2(a, b);
    }
    kf[f] = k;
  }
  __syncthreads();
  markov_body(initial, transition, tmat, kf, out, N, nf);
}

extern "C" void kernel_launch(void* const* d_in, const int* in_sizes, int n_in,
                              void* d_out, int out_size, void* d_ws, size_t ws_size,
                              hipStream_t stream) {
  const float* initial    = (const float*)d_in[0];
  const float* transition = (const float*)d_in[1];
  const float* tmat       = (const float*)d_in[2];
  float* out = (float*)d_out;

  const int N  = in_sizes[0] / 2;               // 200000 emitters
  const int nf = (N > 0) ? (out_size / N) : 0;  // 500 frames
  if (N <= 0 || nf <= 0) return;

  const int nthreads = (N + 1) / 2;             // one thread per emitter pair
  const int block = 64;
  const int grid = (nthreads + block - 1) / block;   // 1563 waves

  const size_t need = (size_t)(nf + 1) * sizeof(uint2);
  if (ws_size >= need) {
    uint2* ks = (uint2*)d_ws;
    subkeys_kernel<<<(nf + 1 + 255) / 256, 256, 0, stream>>>(ks, nf);
    markov_kernel<<<grid, block, 0, stream>>>(initial, transition, tmat, ks,
                                              out, N, nf);
  } else {
    markov_kernel_lds<<<grid, block, need, stream>>>(initial, transition,
                                                     tmat, out, N, nf);
  }
}

// Round 6
// 261.263 us; speedup vs baseline: 1.0994x; 1.0994x over previous
//
#include <hip/hip_runtime.h>
#include <stdint.h>

// SimpleMarkovModel: 2-state Markov chain, 200000 emitters x 500 frames.
// Bit-exact JAX partitionable Threefry-2x32 (verified rounds 1-5, absmax 0).
//
// R6: attack the store-retirement stall.
//  - Nontemporal (nt) output stores: no L2 allocate -> kills the 827 MB
//    read-for-ownership FETCH stream.
//  - 4-frame unroll with 4 independent store-value registers: 4 stores in
//    flight; vmcnt register-recycle wait moves off the per-frame critical
//    path (was: VGPR_Count=12 -> same data reg recycled -> vmcnt(0)/frame).

#define ROTL32(x, d) __builtin_amdgcn_alignbit((x), (x), 32 - (d))

typedef uint32_t v2u __attribute__((ext_vector_type(2)));

__device__ __forceinline__ void tf2x32(uint32_t k0, uint32_t k1,
                                       uint32_t x0, uint32_t x1,
                                       uint32_t& o0, uint32_t& o1) {
  const uint32_t k2 = k0 ^ k1 ^ 0x1BD11BDAu;
  x0 += k0; x1 += k1;
#define TF_R(d) { x0 += x1; x1 = ROTL32(x1, d) ^ x0; }
  TF_R(13) TF_R(15) TF_R(26) TF_R(6)
  x0 += k1; x1 += k2 + 1u;
  TF_R(17) TF_R(29) TF_R(16) TF_R(24)
  x0 += k2; x1 += k0 + 2u;
  TF_R(13) TF_R(15) TF_R(26) TF_R(6)
  x0 += k0; x1 += k1 + 3u;
  TF_R(17) TF_R(29) TF_R(16) TF_R(24)
  x0 += k1; x1 += k2 + 4u;
  TF_R(13) TF_R(15) TF_R(26) TF_R(6)
  x0 += k2; x1 += k0 + 5u;
#undef TF_R
  o0 = x0; o1 = x1;
}

// Subkey table, zero-padded to cap so group prefetch never branches.
__global__ void subkeys_kernel(uint2* __restrict__ ks, int nf, int cap) {
  const int f = blockIdx.x * blockDim.x + threadIdx.x;
  if (f < nf) {
    uint32_t a, b;
    tf2x32(0u, 42u, 0u, (uint32_t)f, a, b);
    ks[f] = make_uint2(a, b);
  } else if (f < cap) {
    ks[f] = make_uint2(0u, 0u);
  }
}

// One frame, two interleaved chains; returns packed {outA,outB} bits.
__device__ __forceinline__ v2u do_frame(
    uint32_t k0, uint32_t k1, uint32_t& sA, uint32_t& sB,
    uint32_t& thrA, uint32_t& thrB, uint32_t baseA, uint32_t baseB,
    uint32_t tsh0, uint32_t tsh1, uint32_t sw0, uint32_t sw1) {
  const uint32_t k2 = k0 ^ k1 ^ 0x1BD11BDAu;
  const uint32_t c1 = k2 + 1u, c2 = k0 + 2u, c3 = k1 + 3u,
                 c4 = k2 + 4u, c5 = k0 + 5u;

  uint32_t xa0 = k0, xa1 = baseA + sA + k1;   // v_add3
  uint32_t xb0 = k0, xb1 = baseB + sB + k1;

#define RND(d) { xa0 += xa1; xa1 = ROTL32(xa1, (d)) ^ xa0;   \
                 xb0 += xb1; xb1 = ROTL32(xb1, (d)) ^ xb0; }
  RND(13) RND(15) RND(26) RND(6)
  xa0 += k1; xa1 += c1; xb0 += k1; xb1 += c1;
  RND(17) RND(29) RND(16) RND(24)
  xa0 += k2; xa1 += c2; xb0 += k2; xb1 += c2;
  RND(13) RND(15) RND(26) RND(6)
  xa0 += k0; xa1 += c3; xb0 += k0; xb1 += c3;
  RND(17) RND(29) RND(16) RND(24)
  xa0 += k1; xa1 += c4; xb0 += k1; xb1 += c4;
  RND(13) RND(15) RND(26) RND(6)
  xa0 += k2; xa1 += c5; xb0 += k2; xb1 += c5;
#undef RND

  sA ^= ((xa0 ^ xa1) < thrA) ? sw1 : sw0;
  sB ^= ((xb0 ^ xb1) < thrB) ? sw1 : sw0;
  thrA = sA ? tsh1 : tsh0;
  thrB = sB ? tsh1 : tsh0;
  v2u v;
  v.x = sA ? 0u : 0x3f800000u;
  v.y = sB ? 0u : 0x3f800000u;
  return v;
}

__device__ __forceinline__ void markov_body(
    const float* __restrict__ initial, const float* __restrict__ transition,
    const float* __restrict__ tmat, const uint2* __restrict__ ks,
    float* __restrict__ out, int N, int nf) {
  const int t = blockIdx.x * blockDim.x + threadIdx.x;
  const int nA = 2 * t;          // two consecutive emitters per thread
  const int nB = 2 * t + 1;
  if (nA >= N) return;
  const bool hasB = (nB < N);    // false only for odd-N tail lane

  // u < p  <=>  bits < (ceil(p*2^23) << 9); clamp guards p ~ 1.0.
  const uint64_t t0w = ((uint64_t)(uint32_t)ceilf(transition[1] * 8388608.0f)) << 9;
  const uint64_t t1w = ((uint64_t)(uint32_t)ceilf(transition[3] * 8388608.0f)) << 9;
  const uint32_t tsh0 = (t0w > 0xFFFFFFFFull) ? 0xFFFFFFFFu : (uint32_t)t0w;
  const uint32_t tsh1 = (t1w > 0xFFFFFFFFull) ? 0xFFFFFFFFu : (uint32_t)t1w;
  const uint32_t sw0 = (tmat[1] != 0.0f) ? 1u : 0u;  // matrix 0 swaps?
  const uint32_t sw1 = (tmat[5] != 0.0f) ? 1u : 0u;  // matrix 1 swaps?

  uint32_t sA = (initial[2 * nA] != 0.0f) ? 0u : 1u;
  uint32_t sB = hasB ? ((initial[2 * nB] != 0.0f) ? 0u : 1u) : 0u;
  uint32_t thrA = sA ? tsh1 : tsh0;
  uint32_t thrB = sB ? tsh1 : tsh0;
  const uint32_t baseA = 2u * (uint32_t)nA;
  const uint32_t baseB = 2u * (uint32_t)nB;

  float* op = out + nA;               // advances by N per frame
  const uint4* kq = (const uint4*)ks; // 2 subkeys per uint4

  const int ng = nf / 4;
  uint4 a0 = kq[0], a1 = kq[1];
  if (hasB) {
    for (int g = 0; g < ng; ++g) {
      const uint4 b0 = kq[2 * g + 2];   // next group (padded)
      const uint4 b1 = kq[2 * g + 3];
      // 4 frames with 4 independent value regs; nt stores (no L2 allocate).
      const v2u v0 = do_frame(a0.x, a0.y, sA, sB, thrA, thrB, baseA, baseB,
                              tsh0, tsh1, sw0, sw1);
      __builtin_nontemporal_store(v0, (v2u*)op); op += N;
      const v2u v1 = do_frame(a0.z, a0.w, sA, sB, thrA, thrB, baseA, baseB,
                              tsh0, tsh1, sw0, sw1);
      __builtin_nontemporal_store(v1, (v2u*)op); op += N;
      const v2u v2 = do_frame(a1.x, a1.y, sA, sB, thrA, thrB, baseA, baseB,
                              tsh0, tsh1, sw0, sw1);
      __builtin_nontemporal_store(v2, (v2u*)op); op += N;
      const v2u v3 = do_frame(a1.z, a1.w, sA, sB, thrA, thrB, baseA, baseB,
                              tsh0, tsh1, sw0, sw1);
      __builtin_nontemporal_store(v3, (v2u*)op); op += N;
      a0 = b0; a1 = b1;
    }
    for (int f = ng * 4; f < nf; ++f) {
      const uint2 k = ks[f];
      const v2u v = do_frame(k.x, k.y, sA, sB, thrA, thrB, baseA, baseB,
                             tsh0, tsh1, sw0, sw1);
      __builtin_nontemporal_store(v, (v2u*)op); op += N;
    }
  } else {
    for (int f = 0; f < nf; ++f) {
      const uint2 k = ks[f];
      const v2u v = do_frame(k.x, k.y, sA, sB, thrA, thrB, baseA, baseB,
                             tsh0, tsh1, sw0, sw1);
      __builtin_nontemporal_store(v.x, (uint32_t*)op); op += N;
    }
  }
}

__global__ __launch_bounds__(64) void markov_kernel(
    const float* __restrict__ initial, const float* __restrict__ transition,
    const float* __restrict__ tmat, const uint2* __restrict__ ks,
    float* __restrict__ out, int N, int nf) {
  markov_body(initial, transition, tmat, ks, out, N, nf);
}

// Fallback if d_ws too small: subkeys in LDS (same padded layout).
__global__ __launch_bounds__(64) void markov_kernel_lds(
    const float* __restrict__ initial, const float* __restrict__ transition,
    const float* __restrict__ tmat, float* __restrict__ out,
    int N, int nf, int cap) {
  extern __shared__ uint2 kf[];
  for (int f = threadIdx.x; f < cap; f += blockDim.x) {
    uint2 k = make_uint2(0u, 0u);
    if (f < nf) {
      uint32_t a, b;
      tf2x32(0u, 42u, 0u, (uint32_t)f, a, b);
      k = make_uint2(a, b);
    }
    kf[f] = k;
  }
  __syncthreads();
  markov_body(initial, transition, tmat, kf, out, N, nf);
}

extern "C" void kernel_launch(void* const* d_in, const int* in_sizes, int n_in,
                              void* d_out, int out_size, void* d_ws, size_t ws_size,
                              hipStream_t stream) {
  const float* initial    = (const float*)d_in[0];
  const float* transition = (const float*)d_in[1];
  const float* tmat       = (const float*)d_in[2];
  float* out = (float*)d_out;

  const int N  = in_sizes[0] / 2;               // 200000 emitters
  const int nf = (N > 0) ? (out_size / N) : 0;  // 500 frames
  if (N <= 0 || nf <= 0) return;

  const int nthreads = (N + 1) / 2;             // one thread per emitter pair
  const int block = 64;
  const int grid = (nthreads + block - 1) / block;   // 1563 waves

  const int cap = (nf / 4 + 2) * 4;             // padded subkey count
  const size_t need = (size_t)cap * sizeof(uint2);
  if (ws_size >= need) {
    uint2* ks = (uint2*)d_ws;
    subkeys_kernel<<<(cap + 255) / 256, 256, 0, stream>>>(ks, nf, cap);
    markov_kernel<<<grid, block, 0, stream>>>(initial, transition, tmat, ks,
                                              out, N, nf);
  } else {
    markov_kernel_lds<<<grid, block, need, stream>>>(initial, transition,
                                                     tmat, out, N, nf, cap);
  }
}